// Round 3
// baseline (657.462 us; speedup 1.0000x reference)
//
#include <hip/hip_runtime.h>

// RNN-T (Transducer) forward loss, N=16, T=256, U=128, V=256, blank=V-1.
// Two-kernel design, v4:
//   1) rnnt_gather_kernel: block = (t_out, n), lanes walk u. Thread u builds
//      the COMPLETE cell G[n][t][u] = {blank(t-1,u), emit(t,u-1)} * log2(e)
//      with one coalesced float2 store (no partial-line RMW). Reads are
//      1KB-stride walks inside two adjacent 128KB windows (DRAM page-local).
//      Boundary cells (t==0 .x, u==0 .y, t==T .y) get NEGF -> G fully init'd.
//   2) rnnt_diag_kernel: anti-diagonal wavefront, 1 wave/example, 2 u/lane,
//      per-cell operands fetched as one float2 from the L2/L3-resident G
//      (prefetch ring depth 16), cross-lane neighbor via DPP wave_shr:1
//      (VALU-pipe, ~4cy vs ~30cy ds_permute), base-2 log-sum-exp.

#define T_DIM 256
#define U_DIM 128
#define V_DIM 256
#define UV (U_DIM * V_DIM)      // 32768
#define GROWS (T_DIM + 1)       // 257 rows of G, t index 0..256
#define NEGF (-1e30f)
#define LOG2E 1.44269504088896340736f
#define LN2F  0.69314718055994530942f

// base-2 log-sum-exp: inputs/outputs scaled by log2(e)
__device__ __forceinline__ float lse2b2(float x, float y) {
    float m = fmaxf(x, y);
    float t = __builtin_amdgcn_exp2f(-fabsf(x - y));
    return m + __builtin_amdgcn_logf(1.0f + t);   // v_log_f32 == log2
}

// shfl_up by 1 across the full 64-lane wave via DPP wave_shr:1 (ctrl 0x138).
// Lane 0 keeps its own value (old == src); consumers mask lane 0 anyway.
__device__ __forceinline__ float wave_shr1(float x) {
    int xi = __float_as_int(x);
    int r = __builtin_amdgcn_update_dpp(xi, xi, 0x138, 0xF, 0xF, false);
    return __int_as_float(r);
}

// G[n][t][u].x = log2e * log_probs[n, t-1, u, V-1]         (vertical move into (t,u))
// G[n][t][u].y = log2e * log_probs[n, t, u-1, labels[u-1]]  (horizontal move into (t,u))
__global__ __launch_bounds__(128) void rnnt_gather_kernel(
        const float* __restrict__ lp, const int* __restrict__ labels,
        float2* __restrict__ G) {
    const int t = blockIdx.x;          // 0..256 (output row of G)
    const int n = blockIdx.y;
    const int u = threadIdx.x;         // 0..127

    float x = NEGF, y = NEGF;
    if (t >= 1) {
        // blank(t-1, u)
        x = lp[((size_t)(n * T_DIM + (t - 1)) * U_DIM + u) * V_DIM + (V_DIM - 1)]
            * LOG2E;
    }
    if (u >= 1 && t < T_DIM) {
        // emit(t, u-1)
        const int lbl = labels[n * (U_DIM - 1) + (u - 1)];
        y = lp[((size_t)(n * T_DIM + t) * U_DIM + (u - 1)) * V_DIM + lbl] * LOG2E;
    }
    G[(size_t)n * GROWS * U_DIM + t * U_DIM + u] = make_float2(x, y);
}

__global__ __launch_bounds__(64, 1) void rnnt_diag_kernel(
        const float* __restrict__ lp, const float2* __restrict__ G,
        const int* __restrict__ lengths, const int* __restrict__ lab_lens,
        float* __restrict__ out, float inv_n) {
    const int n    = blockIdx.x;
    const int lane = threadIdx.x;
    const int u0   = lane * 2;
    const int u1   = u0 + 1;

    const float2* Gn = G + (size_t)n * GROWS * U_DIM;
    const float2* g0 = Gn + u0;
    const float2* g1 = Gn + u1;

    const int t_len = lengths[n];
    const int u_len = lab_lens[n];
    const int dstar = (t_len - 1) + u_len;   // in [127, 382] here

    // Final blank log-prob: address known at entry -- issue the (cold) HBM
    // load now so its ~900cy latency hides under the whole sweep.
    const float bl = lp[(size_t)n * T_DIM * UV + (size_t)(t_len - 1) * UV
                        + u_len * V_DIM + (V_DIM - 1)];

    float a0 = (lane == 0) ? 0.0f : NEGF;    // alpha[0,0] at diagonal 0 (base-2 scale)
    float a1 = NEGF;
    float res = NEGF;
    if (dstar == 0 && lane == 0) res = a0;   // safety (unreachable here)

    float nb = wave_shr1(a1);                // neighbor a1 from previous lane

    constexpr int PF = 16;
    float2 bufG0[PF], bufG1[PF];

    auto issue = [&](int d, int slot) {
        // operands of cells (d-u0, u0) and (d-u1, u1); clamp t for address safety
        const int t0 = min(max(d - u0, 0), GROWS - 1);
        const int t1 = min(max(d - u1, 0), GROWS - 1);
        bufG0[slot] = g0[t0 * U_DIM];        // {blank(t0-1,u0), emit(t0,u0-1)}
        bufG1[slot] = g1[t1 * U_DIM];        // {blank(t1-1,u1), emit(t1,u1-1)}
    };

#pragma unroll
    for (int j = 0; j < PF; ++j) issue(1 + j, j);

    // diagonals d = 1..384 (padded past 382; extras masked to NEG)
    for (int dd = 1; dd < 385; dd += PF) {
#pragma unroll
        for (int j = 0; j < PF; ++j) {
            const int d = dd + j;                    // slot == j
            const int t0 = d - u0;
            const int t1 = d - u1;
            const bool vb0 = (unsigned)(t0 - 1) < (unsigned)(T_DIM - 1); // t0 in [1,T-1]
            const bool vb1 = (unsigned)(t1 - 1) < (unsigned)(T_DIM - 1);
            const bool ve0 = (u0 >= 1) && ((unsigned)t0 < (unsigned)T_DIM);
            const bool ve1 = ((unsigned)t1 < (unsigned)T_DIM);

            const float pa0 = vb0 ? (a0 + bufG0[j].x) : NEGF;
            const float pb0 = ve0 ? (nb + bufG0[j].y) : NEGF;
            const float na0 = lse2b2(pa0, pb0);

            const float pa1 = vb1 ? (a1 + bufG1[j].x) : NEGF;
            const float pb1 = ve1 ? (a0 + bufG1[j].y) : NEGF;  // OLD a0
            const float na1 = lse2b2(pa1, pb1);

            a0 = na0;
            a1 = na1;
            nb = wave_shr1(a1);                      // for next iteration

            issue(d + PF, j);                        // refill slot

            if (d == dstar) {                        // uniform scalar branch
                if (u_len == u0)      res = na0;
                else if (u_len == u1) res = na1;
            }
        }
    }

    if (lane == (u_len >> 1)) {
        atomicAdd(out, -(res * LN2F + bl) * inv_n);  // rescale base-2 -> natural log
    }
}

extern "C" void kernel_launch(void* const* d_in, const int* in_sizes, int n_in,
                              void* d_out, int out_size, void* d_ws, size_t ws_size,
                              hipStream_t stream) {
    const float* lp      = (const float*)d_in[0];
    const int*   labels  = (const int*)d_in[1];
    const int*   lengths = (const int*)d_in[2];
    const int*   lablens = (const int*)d_in[3];
    float* out = (float*)d_out;
    const int N = in_sizes[2];

    float2* G = (float2*)d_ws;                       // N*257*128*8 B = 4.2 MB

    hipMemsetAsync(d_out, 0, sizeof(float), stream);
    rnnt_gather_kernel<<<dim3(GROWS, N), dim3(128), 0, stream>>>(lp, labels, G);
    rnnt_diag_kernel<<<dim3(N), dim3(64), 0, stream>>>(
        lp, G, lengths, lablens, out, 1.0f / (float)N);
}

// Round 4
// 645.936 us; speedup vs baseline: 1.0178x; 1.0178x over previous
//
#include <hip/hip_runtime.h>

// RNN-T (Transducer) forward loss, N=16, T=256, U=128, V=256, blank=V-1.
// Three-kernel design, v5:
//   1) rnnt_gather_kernel: block = (t_out, n), lanes walk u. Thread u builds
//      the COMPLETE cell G[n][t][u] = {blank(t-1,u), emit(t,u-1)} * log2(e)
//      with one coalesced float2 store. Reads are 1KB-stride walks inside two
//      adjacent 128KB windows (DRAM page-local). Boundary cells get NEGF.
//   2) rnnt_relayout_kernel: block = (e, n). Transposes row-major G into
//      diagonal-major Gd[n][e][u] = G[n][e-u][u] (NEGF outside). Scattered
//      READS (latency hidden by 6144 parallel blocks), fully coalesced
//      writes, each block owns its output row (no cross-block line sharing).
//   3) rnnt_diag_kernel: anti-diagonal wavefront, 1 wave/example, 2 u/lane.
//      Per diagonal the wave issues ONE coalesced global_load_dwordx4
//      (lane l gets {B(u0),E(u0),B(u1),E(u1)} of row e) through a depth-16
//      prefetch ring -- no per-step scatter, cross-lane neighbor via DPP
//      wave_shr:1, base-2 log-sum-exp.

#define T_DIM 256
#define U_DIM 128
#define V_DIM 256
#define UV (U_DIM * V_DIM)      // 32768
#define GROWS (T_DIM + 1)       // 257 rows of G, t index 0..256
#define E_ROWS 384              // diagonals 0..382, padded to 384
#define NEGF (-1e30f)
#define LOG2E 1.44269504088896340736f
#define LN2F  0.69314718055994530942f

// base-2 log-sum-exp: inputs/outputs scaled by log2(e)
__device__ __forceinline__ float lse2b2(float x, float y) {
    float m = fmaxf(x, y);
    float t = __builtin_amdgcn_exp2f(-fabsf(x - y));
    return m + __builtin_amdgcn_logf(1.0f + t);   // v_log_f32 == log2
}

// shfl_up by 1 across the full 64-lane wave via DPP wave_shr:1 (ctrl 0x138).
// Lane 0 keeps its own value (old == src); consumers mask lane 0 anyway.
__device__ __forceinline__ float wave_shr1(float x) {
    int xi = __float_as_int(x);
    int r = __builtin_amdgcn_update_dpp(xi, xi, 0x138, 0xF, 0xF, false);
    return __int_as_float(r);
}

// G[n][t][u].x = log2e * log_probs[n, t-1, u, V-1]         (vertical move into (t,u))
// G[n][t][u].y = log2e * log_probs[n, t, u-1, labels[u-1]]  (horizontal move into (t,u))
__global__ __launch_bounds__(128) void rnnt_gather_kernel(
        const float* __restrict__ lp, const int* __restrict__ labels,
        float2* __restrict__ G) {
    const int t = blockIdx.x;          // 0..256 (output row of G)
    const int n = blockIdx.y;
    const int u = threadIdx.x;         // 0..127

    float x = NEGF, y = NEGF;
    if (t >= 1) {
        // blank(t-1, u)
        x = lp[((size_t)(n * T_DIM + (t - 1)) * U_DIM + u) * V_DIM + (V_DIM - 1)]
            * LOG2E;
    }
    if (u >= 1 && t < T_DIM) {
        // emit(t, u-1)
        const int lbl = labels[n * (U_DIM - 1) + (u - 1)];
        y = lp[((size_t)(n * T_DIM + t) * U_DIM + (u - 1)) * V_DIM + lbl] * LOG2E;
    }
    G[(size_t)n * GROWS * U_DIM + t * U_DIM + u] = make_float2(x, y);
}

// Gd[n][e][u] = G[n][e-u][u] when 0 <= e-u <= T_DIM, else {NEGF,NEGF}.
__global__ __launch_bounds__(128) void rnnt_relayout_kernel(
        const float2* __restrict__ G, float2* __restrict__ Gd) {
    const int e = blockIdx.x;          // 0..383
    const int n = blockIdx.y;
    const int u = threadIdx.x;         // 0..127
    const int t = e - u;
    float2 v = make_float2(NEGF, NEGF);
    if ((unsigned)t <= (unsigned)T_DIM)
        v = G[(size_t)n * GROWS * U_DIM + t * U_DIM + u];
    Gd[(size_t)n * E_ROWS * U_DIM + e * U_DIM + u] = v;
}

__global__ __launch_bounds__(64, 1) void rnnt_diag_kernel(
        const float* __restrict__ lp, const float2* __restrict__ Gd,
        const int* __restrict__ lengths, const int* __restrict__ lab_lens,
        float* __restrict__ out, float inv_n) {
    const int n    = blockIdx.x;
    const int lane = threadIdx.x;
    const int u0   = lane * 2;
    const int u1   = u0 + 1;

    // float4 view: row e = 64 float4; lane l owns {B(u0),E(u0),B(u1),E(u1)}
    const float4* Gdn = (const float4*)(Gd + (size_t)n * E_ROWS * U_DIM);

    const int t_len = lengths[n];
    const int u_len = lab_lens[n];
    const int dstar = (t_len - 1) + u_len;   // in [127, 382] here

    // Final blank log-prob: address known at entry -- issue the (cold) HBM
    // load now so its ~900cy latency hides under the whole sweep.
    const float bl = lp[(size_t)n * T_DIM * UV + (size_t)(t_len - 1) * UV
                        + u_len * V_DIM + (V_DIM - 1)];

    float a0 = (lane == 0) ? 0.0f : NEGF;    // alpha[0,0] at diagonal 0 (base-2 scale)
    float a1 = NEGF;
    float res = NEGF;
    if (dstar == 0 && lane == 0) res = a0;   // safety (unreachable here)

    float nb = wave_shr1(a1);                // neighbor a1 from previous lane

    constexpr int PF = 16;
    float4 buf[PF];

    auto issue = [&](int d, int slot) {
        const int e = min(d, E_ROWS - 1);    // clamp for address safety
        buf[slot] = Gdn[(size_t)e * 64 + lane];  // one coalesced dwordx4 / lane
    };

#pragma unroll
    for (int j = 0; j < PF; ++j) issue(1 + j, j);

    // diagonals d = 1..384 (padded past 382; extras masked to NEG)
    for (int dd = 1; dd < 385; dd += PF) {
#pragma unroll
        for (int j = 0; j < PF; ++j) {
            const int d = dd + j;                    // slot == j
            const int t0 = d - u0;
            const int t1 = d - u1;
            const bool vb0 = (unsigned)(t0 - 1) < (unsigned)(T_DIM - 1); // t0 in [1,T-1]
            const bool vb1 = (unsigned)(t1 - 1) < (unsigned)(T_DIM - 1);
            const bool ve0 = (u0 >= 1) && ((unsigned)t0 < (unsigned)T_DIM);
            const bool ve1 = ((unsigned)t1 < (unsigned)T_DIM);

            const float pa0 = vb0 ? (a0 + buf[j].x) : NEGF;
            const float pb0 = ve0 ? (nb + buf[j].y) : NEGF;
            const float na0 = lse2b2(pa0, pb0);

            const float pa1 = vb1 ? (a1 + buf[j].z) : NEGF;
            const float pb1 = ve1 ? (a0 + buf[j].w) : NEGF;  // OLD a0
            const float na1 = lse2b2(pa1, pb1);

            a0 = na0;
            a1 = na1;
            nb = wave_shr1(a1);                      // for next iteration

            issue(d + PF, j);                        // refill slot

            if (d == dstar) {                        // uniform scalar branch
                if (u_len == u0)      res = na0;
                else if (u_len == u1) res = na1;
            }
        }
    }

    if (lane == (u_len >> 1)) {
        atomicAdd(out, -(res * LN2F + bl) * inv_n);  // rescale base-2 -> natural log
    }
}

extern "C" void kernel_launch(void* const* d_in, const int* in_sizes, int n_in,
                              void* d_out, int out_size, void* d_ws, size_t ws_size,
                              hipStream_t stream) {
    const float* lp      = (const float*)d_in[0];
    const int*   labels  = (const int*)d_in[1];
    const int*   lengths = (const int*)d_in[2];
    const int*   lablens = (const int*)d_in[3];
    float* out = (float*)d_out;
    const int N = in_sizes[2];

    float2* G  = (float2*)d_ws;                      // N*257*128*8 B = 4.2 MB
    float2* Gd = G + (size_t)N * GROWS * U_DIM;      // N*384*128*8 B = 6.3 MB

    hipMemsetAsync(d_out, 0, sizeof(float), stream);
    rnnt_gather_kernel<<<dim3(GROWS, N), dim3(128), 0, stream>>>(lp, labels, G);
    rnnt_relayout_kernel<<<dim3(E_ROWS, N), dim3(128), 0, stream>>>(G, Gd);
    rnnt_diag_kernel<<<dim3(N), dim3(64), 0, stream>>>(
        lp, Gd, lengths, lablens, out, 1.0f / (float)N);
}